// Round 1
// baseline (588.806 us; speedup 1.0000x reference)
//
#include <hip/hip_runtime.h>
#include <stdint.h>

#define NROWS 32768   // B*H*W
#define CDIM  512
#define KCODES 1024
#define VC    512

typedef unsigned short u16;
using bf16x8 = __attribute__((ext_vector_type(8))) __bf16;
using f32x4  = __attribute__((ext_vector_type(4))) float;

__device__ __forceinline__ float bf2f(u16 u){
  union { unsigned int i; float f; } x; x.i = ((unsigned int)u) << 16; return x.f;
}
__device__ __forceinline__ u16 f2bf(float f){
  union { float f; unsigned int i; } x; x.f = f;
  unsigned int u = x.i;
  u += 0x7fffu + ((u >> 16) & 1u);   // RNE, no NaN inputs expected
  return (u16)(u >> 16);
}
__device__ __forceinline__ unsigned int pack2(u16 lo, u16 hi){
  return (unsigned int)lo | ((unsigned int)hi << 16);
}
__device__ __forceinline__ f32x4 mfma16(bf16x8 a, bf16x8 b, f32x4 c){
  return __builtin_amdgcn_mfma_f32_16x16x32_bf16(a, b, c, 0, 0, 0);
}

// ---------------- K1: transpose x (B,C,H,W) -> xf bf16 (N=32768, C=512) ---
__global__ __launch_bounds__(256) void k_transpose_x(const float* __restrict__ x,
                                                     u16* __restrict__ xf){
  __shared__ float tile[32][33];
  int b  = blockIdx.z;
  int p0 = blockIdx.x * 32;       // hw index within image (HW=4096)
  int c0 = blockIdx.y * 32;
  int tx = threadIdx.x, ty = threadIdx.y;   // (32, 8)
  const float* xb = x + (size_t)b * CDIM * 4096;
#pragma unroll
  for (int i = 0; i < 4; i++){
    int c = c0 + ty + i * 8;
    tile[ty + i * 8][tx] = xb[(size_t)c * 4096 + p0 + tx];
  }
  __syncthreads();
#pragma unroll
  for (int i = 0; i < 4; i++){
    int p = p0 + ty + i * 8;
    xf[((size_t)(b * 4096 + p)) * CDIM + c0 + tx] = f2bf(tile[tx][ty + i * 8]);
  }
}

// ---------------- K2: per-row 1/||x|| from xf bf16 ------------------------
__global__ __launch_bounds__(256) void k_rownorm(const u16* __restrict__ xf,
                                                 float* __restrict__ rinv){
  int row  = blockIdx.x * 4 + (threadIdx.x >> 6);
  int lane = threadIdx.x & 63;
  const uint4* p = (const uint4*)(xf + (size_t)row * CDIM);
  uint4 v = p[lane];                       // 8 bf16 per lane, 64 lanes = 512
  unsigned int w[4] = {v.x, v.y, v.z, v.w};
  float s = 0.f;
#pragma unroll
  for (int i = 0; i < 4; i++){
    float a = bf2f((u16)(w[i] & 0xffffu));
    float b = bf2f((u16)(w[i] >> 16));
    s += a * a + b * b;
  }
#pragma unroll
  for (int off = 32; off; off >>= 1) s += __shfl_xor(s, off, 64);
  if (lane == 0) rinv[row] = 1.0f / fmaxf(sqrtf(s), 1e-12f);
}

// ---------------- K3: normalize noise_feature rows -> mn bf16 -------------
__global__ __launch_bounds__(256) void k_norm_rows(const float* __restrict__ in,
                                                   u16* __restrict__ out){
  int row  = blockIdx.x * 4 + (threadIdx.x >> 6);
  int lane = threadIdx.x & 63;
  const float* r = in + (size_t)row * CDIM;
  float v[8]; float s = 0.f;
#pragma unroll
  for (int i = 0; i < 8; i++){ v[i] = r[lane + i * 64]; s += v[i] * v[i]; }
#pragma unroll
  for (int off = 32; off; off >>= 1) s += __shfl_xor(s, off, 64);
  float inv = 1.0f / fmaxf(sqrtf(s), 1e-12f);
#pragma unroll
  for (int i = 0; i < 8; i++) out[(size_t)row * CDIM + lane + i * 64] = f2bf(v[i] * inv);
}

// ---------------- K3b: transpose std (1024,512) -> stdT bf16 (512,1024) ---
__global__ __launch_bounds__(256) void k_transpose_std(const float* __restrict__ sd,
                                                       u16* __restrict__ stdT){
  __shared__ float tile[32][33];
  int k0 = blockIdx.x * 32;   // code dim
  int v0 = blockIdx.y * 32;   // vc dim
  int tx = threadIdx.x, ty = threadIdx.y;
#pragma unroll
  for (int i = 0; i < 4; i++)
    tile[ty + i * 8][tx] = sd[(size_t)(k0 + ty + i * 8) * VC + v0 + tx];
  __syncthreads();
#pragma unroll
  for (int i = 0; i < 4; i++)
    stdT[(size_t)(v0 + ty + i * 8) * KCODES + k0 + tx] = f2bf(tile[tx][ty + i * 8]);
}

// ---------------- K4: GEMM1 (xf @ mn^T) + argmax + segment atomics --------
// 256 blocks, 128 rows each. A-slab 128x512 resident in LDS (padded 520).
#define AS_LD 520
#define BS_LD 72
__global__ __launch_bounds__(256) void k_gemm1_argmax(const u16* __restrict__ xf,
                                                      const u16* __restrict__ mn,
                                                      float* __restrict__ esum,
                                                      float* __restrict__ counts){
  extern __shared__ u16 smem[];
  u16*   As    = smem;                           // 128*520
  u16*   Bs    = As + 128 * AS_LD;               // 128*72
  float* candv = (float*)(Bs + 128 * BS_LD);     // [2][128]
  int*   candi = (int*)(candv + 256);            // [2][128]
  float* bestv = (float*)(candi + 256);          // [128]
  int*   besti = (int*)(bestv + 128);            // [128]

  int tid  = threadIdx.x;
  int wave = tid >> 6, lane = tid & 63;
  int wr = wave >> 1, wc = wave & 1;
  int quad = lane >> 4, l15 = lane & 15;
  int r0 = blockIdx.x * 128;

  { // stage A slab once
    int row = tid >> 1, half = tid & 1;
    const uint4* src = (const uint4*)(xf + (size_t)(r0 + row) * CDIM);
#pragma unroll 8
    for (int jj = 0; jj < 32; jj++){
      int j = half + 2 * jj;
      *((uint4*)(As + row * AS_LD + j * 8)) = src[j];
    }
  }
  if (tid < 128){ bestv[tid] = -1e30f; besti[tid] = 0x7fffffff; }
  __syncthreads();

  for (int nt = 0; nt < 8; nt++){
    f32x4 acc[4][4];
#pragma unroll
    for (int rt = 0; rt < 4; rt++)
#pragma unroll
      for (int ct = 0; ct < 4; ct++) acc[rt][ct] = (f32x4)(0.f);

    for (int k0 = 0; k0 < CDIM; k0 += 64){
      { // stage B tile (codes nt*128.., k0..k0+63)
        int row = tid >> 1, half = tid & 1;
        const uint4* src = (const uint4*)(mn + (size_t)(nt * 128 + row) * CDIM + k0 + half * 32);
        uint4* dst = (uint4*)(Bs + row * BS_LD + half * 32);
#pragma unroll
        for (int j = 0; j < 4; j++) dst[j] = src[j];
      }
      __syncthreads();
#pragma unroll
      for (int ks = 0; ks < 2; ks++){
        bf16x8 af[4], bf[4];
#pragma unroll
        for (int rt = 0; rt < 4; rt++)
          af[rt] = *(const bf16x8*)(As + (wr * 64 + rt * 16 + l15) * AS_LD + k0 + ks * 32 + quad * 8);
#pragma unroll
        for (int ct = 0; ct < 4; ct++)
          bf[ct] = *(const bf16x8*)(Bs + (wc * 64 + ct * 16 + l15) * BS_LD + ks * 32 + quad * 8);
#pragma unroll
        for (int rt = 0; rt < 4; rt++)
#pragma unroll
          for (int ct = 0; ct < 4; ct++)
            acc[rt][ct] = mfma16(af[rt], bf[ct], acc[rt][ct]);
      }
      __syncthreads();
    }

    // argmax epilogue for this N-tile
#pragma unroll
    for (int rt = 0; rt < 4; rt++){
#pragma unroll
      for (int q = 0; q < 4; q++){
        float bv = acc[rt][0][q];
        int   bc = nt * 128 + wc * 64 + l15;      // ct=0
#pragma unroll
        for (int ct = 1; ct < 4; ct++){
          float v = acc[rt][ct][q];
          int   c = nt * 128 + wc * 64 + ct * 16 + l15;
          if (v > bv){ bv = v; bc = c; }           // ascending c: ties keep first
        }
#pragma unroll
        for (int off = 1; off <= 8; off <<= 1){
          float ov = __shfl_xor(bv, off, 64);
          int   oc = __shfl_xor(bc, off, 64);
          if (ov > bv || (ov == bv && oc < bc)){ bv = ov; bc = oc; }
        }
        if (l15 == 0){
          int r = wr * 64 + rt * 16 + quad * 4 + q;
          candv[wc * 128 + r] = bv; candi[wc * 128 + r] = bc;
        }
      }
    }
    __syncthreads();
    if (tid < 128){
      float bv = bestv[tid]; int bc = besti[tid];
#pragma unroll
      for (int s = 0; s < 2; s++){
        float v = candv[s * 128 + tid]; int c = candi[s * 128 + tid];
        if (v > bv || (v == bv && c < bc)){ bv = v; bc = c; }
      }
      bestv[tid] = bv; besti[tid] = bc;
    }
    __syncthreads();
  }

  // segment-sum: counts + embed_sum (bf16 values from the resident A slab)
  if (tid < 128) atomicAdd(&counts[besti[tid]], 1.0f);
  for (int r = 0; r < 128; r++){
    int code = besti[r];
    float* dst = esum + (size_t)code * CDIM;
    for (int c = tid; c < CDIM; c += 256)
      atomicAdd(dst + c, bf2f(As[r * AS_LD + c]));
  }
}

// ---------------- K6: new_m = m*0.999 + mean*0.001; normalize -> mn2 bf16 -
__global__ __launch_bounds__(256) void k_newm(const float* __restrict__ m,
                                              const float* __restrict__ esum,
                                              const float* __restrict__ counts,
                                              u16* __restrict__ mn2){
  int row  = blockIdx.x * 4 + (threadIdx.x >> 6);
  int lane = threadIdx.x & 63;
  float cnt = counts[row];
  float sc  = 0.001f / (cnt + 1e-6f);
  float v[8]; float s = 0.f;
#pragma unroll
  for (int i = 0; i < 8; i++){
    int c = lane + i * 64;
    v[i] = m[(size_t)row * CDIM + c] * 0.999f + esum[(size_t)row * CDIM + c] * sc;
    s += v[i] * v[i];
  }
#pragma unroll
  for (int off = 32; off; off >>= 1) s += __shfl_xor(s, off, 64);
  float inv = 1.0f / fmaxf(sqrtf(s), 1e-12f);
#pragma unroll
  for (int i = 0; i < 8; i++) mn2[(size_t)row * CDIM + lane + i * 64] = f2bf(v[i] * inv);
}

// ---------------- K7: GEMM2 score2 = (xf @ mn2^T) * rinv[row] -> d_out ----
__global__ __launch_bounds__(256) void k_gemm2(const u16* __restrict__ xf,
                                               const u16* __restrict__ mn2,
                                               const float* __restrict__ rinv,
                                               float* __restrict__ score2){
  __shared__ u16 As[128 * BS_LD];
  __shared__ u16 Bs[128 * BS_LD];
  int tid  = threadIdx.x;
  int wave = tid >> 6, lane = tid & 63;
  int wr = wave >> 1, wc = wave & 1;
  int quad = lane >> 4, l15 = lane & 15;
  int r0 = blockIdx.x * 128, c0 = blockIdx.y * 128;
  int row = tid >> 1, half = tid & 1;

  f32x4 acc[4][4];
#pragma unroll
  for (int rt = 0; rt < 4; rt++)
#pragma unroll
    for (int ct = 0; ct < 4; ct++) acc[rt][ct] = (f32x4)(0.f);

  const u16* ag = xf  + (size_t)(r0 + row) * CDIM + half * 32;
  const u16* bg = mn2 + (size_t)(c0 + row) * CDIM + half * 32;

  for (int k0 = 0; k0 < CDIM; k0 += 64){
    const uint4* asrc = (const uint4*)(ag + k0);
    const uint4* bsrc = (const uint4*)(bg + k0);
    uint4* adst = (uint4*)(As + row * BS_LD + half * 32);
    uint4* bdst = (uint4*)(Bs + row * BS_LD + half * 32);
#pragma unroll
    for (int j = 0; j < 4; j++){ adst[j] = asrc[j]; bdst[j] = bsrc[j]; }
    __syncthreads();
#pragma unroll
    for (int ks = 0; ks < 2; ks++){
      bf16x8 af[4], bf[4];
#pragma unroll
      for (int rt = 0; rt < 4; rt++)
        af[rt] = *(const bf16x8*)(As + (wr * 64 + rt * 16 + l15) * BS_LD + ks * 32 + quad * 8);
#pragma unroll
      for (int ct = 0; ct < 4; ct++)
        bf[ct] = *(const bf16x8*)(Bs + (wc * 64 + ct * 16 + l15) * BS_LD + ks * 32 + quad * 8);
#pragma unroll
      for (int rt = 0; rt < 4; rt++)
#pragma unroll
        for (int ct = 0; ct < 4; ct++)
          acc[rt][ct] = mfma16(af[rt], bf[ct], acc[rt][ct]);
    }
    __syncthreads();
  }
#pragma unroll
  for (int rt = 0; rt < 4; rt++){
#pragma unroll
    for (int q = 0; q < 4; q++){
      int grow = r0 + wr * 64 + rt * 16 + quad * 4 + q;
      float rv = rinv[grow];
#pragma unroll
      for (int ct = 0; ct < 4; ct++){
        int gcol = c0 + wc * 64 + ct * 16 + l15;
        score2[(size_t)grow * KCODES + gcol] = acc[rt][ct][q] * rv;
      }
    }
  }
}

// ---------------- K8: softmax stats per row of score2 ---------------------
__global__ __launch_bounds__(256) void k_softstats(const float* __restrict__ score2,
                                                   float* __restrict__ rowmax,
                                                   float* __restrict__ rsinv){
  int row = blockIdx.x, tid = threadIdx.x;
  int wave = tid >> 6, lane = tid & 63;
  float4 v = ((const float4*)(score2 + (size_t)row * KCODES))[tid];
  float mx = fmaxf(fmaxf(v.x, v.y), fmaxf(v.z, v.w));
#pragma unroll
  for (int off = 32; off; off >>= 1) mx = fmaxf(mx, __shfl_xor(mx, off, 64));
  __shared__ float red[4], red2[4];
  if (lane == 0) red[wave] = mx;
  __syncthreads();
  mx = fmaxf(fmaxf(red[0], red[1]), fmaxf(red[2], red[3]));
  float s = __expf(v.x - mx) + __expf(v.y - mx) + __expf(v.z - mx) + __expf(v.w - mx);
#pragma unroll
  for (int off = 32; off; off >>= 1) s += __shfl_xor(s, off, 64);
  if (lane == 0) red2[wave] = s;
  __syncthreads();
  if (tid == 0){ rowmax[row] = mx; rsinv[row] = 1.0f / (red2[0] + red2[1] + red2[2] + red2[3]); }
}

// ---------------- K9: out = softmax(score2) @ std  (exp fused in staging) -
__global__ __launch_bounds__(256) void k_gemm3(const float* __restrict__ score2,
                                               const float* __restrict__ rowmax,
                                               const float* __restrict__ rsinv,
                                               const u16* __restrict__ stdT,
                                               float* __restrict__ out){
  __shared__ u16 As[128 * BS_LD];
  __shared__ u16 Bs[128 * BS_LD];
  int tid  = threadIdx.x;
  int wave = tid >> 6, lane = tid & 63;
  int wr = wave >> 1, wc = wave & 1;
  int quad = lane >> 4, l15 = lane & 15;
  int r0 = blockIdx.x * 128, c0 = blockIdx.y * 128;
  int row = tid >> 1, half = tid & 1;

  float rmax = rowmax[r0 + row];
  float rs   = rsinv [r0 + row];

  f32x4 acc[4][4];
#pragma unroll
  for (int rt = 0; rt < 4; rt++)
#pragma unroll
    for (int ct = 0; ct < 4; ct++) acc[rt][ct] = (f32x4)(0.f);

  const float* ag = score2 + (size_t)(r0 + row) * KCODES + half * 32;
  const u16*   bg = stdT   + (size_t)(c0 + row) * KCODES + half * 32;

  for (int k0 = 0; k0 < KCODES; k0 += 64){
    const float4* asrc = (const float4*)(ag + k0);
    const uint4*  bsrc = (const uint4*)(bg + k0);
    uint4* adst = (uint4*)(As + row * BS_LD + half * 32);
    uint4* bdst = (uint4*)(Bs + row * BS_LD + half * 32);
#pragma unroll
    for (int j = 0; j < 4; j++){
      float4 a = asrc[2 * j], b = asrc[2 * j + 1];
      uint4 o;
      o.x = pack2(f2bf(__expf(a.x - rmax) * rs), f2bf(__expf(a.y - rmax) * rs));
      o.y = pack2(f2bf(__expf(a.z - rmax) * rs), f2bf(__expf(a.w - rmax) * rs));
      o.z = pack2(f2bf(__expf(b.x - rmax) * rs), f2bf(__expf(b.y - rmax) * rs));
      o.w = pack2(f2bf(__expf(b.z - rmax) * rs), f2bf(__expf(b.w - rmax) * rs));
      adst[j] = o;
      bdst[j] = bsrc[j];
    }
    __syncthreads();
#pragma unroll
    for (int ks = 0; ks < 2; ks++){
      bf16x8 af[4], bf[4];
#pragma unroll
      for (int rt = 0; rt < 4; rt++)
        af[rt] = *(const bf16x8*)(As + (wr * 64 + rt * 16 + l15) * BS_LD + ks * 32 + quad * 8);
#pragma unroll
      for (int ct = 0; ct < 4; ct++)
        bf[ct] = *(const bf16x8*)(Bs + (wc * 64 + ct * 16 + l15) * BS_LD + ks * 32 + quad * 8);
#pragma unroll
      for (int rt = 0; rt < 4; rt++)
#pragma unroll
        for (int ct = 0; ct < 4; ct++)
          acc[rt][ct] = mfma16(af[rt], bf[ct], acc[rt][ct]);
    }
    __syncthreads();
  }
#pragma unroll
  for (int rt = 0; rt < 4; rt++){
#pragma unroll
    for (int q = 0; q < 4; q++){
      int grow = r0 + wr * 64 + rt * 16 + quad * 4 + q;
#pragma unroll
      for (int ct = 0; ct < 4; ct++){
        int gcol = c0 + wc * 64 + ct * 16 + l15;
        out[(size_t)grow * VC + gcol] = acc[rt][ct][q];
      }
    }
  }
}

// ---------------- launch ---------------------------------------------------
extern "C" void kernel_launch(void* const* d_in, const int* in_sizes, int n_in,
                              void* d_out, int out_size, void* d_ws, size_t ws_size,
                              hipStream_t stream){
  (void)in_sizes; (void)n_in; (void)out_size; (void)ws_size;
  const float* x      = (const float*)d_in[0];
  const float* m      = (const float*)d_in[1];
  const float* stdmat = (const float*)d_in[2];
  float* out    = (float*)d_out;
  float* score2 = out + (size_t)NROWS * VC;     // outputs concatenated: (out, score2)

  char* ws = (char*)d_ws;
  u16*   xf     = (u16*)  (ws + 0);             // 33,554,432 B
  u16*   mn     = (u16*)  (ws + 33554432);      //  1,048,576 B
  u16*   mn2    = (u16*)  (ws + 34603008);      //  1,048,576 B
  u16*   stdT   = (u16*)  (ws + 35651584);      //  1,048,576 B
  float* rinv   = (float*)(ws + 36700160);      //    131,072 B
  float* esum   = (float*)(ws + 36831232);      //  2,097,152 B
  float* counts = (float*)(ws + 38928384);      //      4,096 B
  float* rowmax = (float*)(ws + 38932480);      //    131,072 B
  float* rsinv  = (float*)(ws + 39063552);      //    131,072 B

  hipMemsetAsync(esum, 0, 2097152 + 4096, stream);   // esum + counts contiguous

  k_transpose_x  <<<dim3(128, 16, 8), dim3(32, 8), 0, stream>>>(x, xf);
  k_rownorm      <<<NROWS / 4, 256, 0, stream>>>(xf, rinv);
  k_norm_rows    <<<KCODES / 4, 256, 0, stream>>>(m, mn);
  k_transpose_std<<<dim3(32, 16), dim3(32, 8), 0, stream>>>(stdmat, stdT);
  k_gemm1_argmax <<<NROWS / 128, 256, 154624, stream>>>(xf, mn, esum, counts);
  k_newm         <<<KCODES / 4, 256, 0, stream>>>(m, esum, counts, mn2);
  k_gemm2        <<<dim3(NROWS / 128, KCODES / 128), 256, 0, stream>>>(xf, mn2, rinv, score2);
  k_softstats    <<<NROWS, 256, 0, stream>>>(score2, rowmax, rsinv);
  k_gemm3        <<<dim3(NROWS / 128, VC / 128), 256, 0, stream>>>(score2, rowmax, rsinv, stdT, out);
}

// Round 2
// 509.789 us; speedup vs baseline: 1.1550x; 1.1550x over previous
//
#include <hip/hip_runtime.h>
#include <stdint.h>

#define NROWS 32768   // B*H*W
#define CDIM  512
#define KCODES 1024
#define VC    512
#define LDP 72        // padded LDS leading dim (elements)

typedef unsigned short u16;
typedef unsigned long long u64;
using bf16x8 = __attribute__((ext_vector_type(8))) __bf16;
using f32x4  = __attribute__((ext_vector_type(4))) float;

__device__ __forceinline__ float bf2f(u16 u){
  union { unsigned int i; float f; } x; x.i = ((unsigned int)u) << 16; return x.f;
}
__device__ __forceinline__ u16 f2bf(float f){
  union { float f; unsigned int i; } x; x.f = f;
  unsigned int u = x.i;
  u += 0x7fffu + ((u >> 16) & 1u);   // RNE
  return (u16)(u >> 16);
}
__device__ __forceinline__ unsigned int pack2(u16 lo, u16 hi){
  return (unsigned int)lo | ((unsigned int)hi << 16);
}
__device__ __forceinline__ unsigned int fkey(float f){
  unsigned int u = __float_as_uint(f);
  return (u & 0x80000000u) ? ~u : (u | 0x80000000u);   // monotone sortable
}
__device__ __forceinline__ f32x4 mfma16(bf16x8 a, bf16x8 b, f32x4 c){
  return __builtin_amdgcn_mfma_f32_16x16x32_bf16(a, b, c, 0, 0, 0);
}

// ---------------- K1: transpose x (B,C,H,W) -> xf bf16 (N=32768, C=512) ---
__global__ __launch_bounds__(256) void k_transpose_x(const float* __restrict__ x,
                                                     u16* __restrict__ xf){
  __shared__ float tile[32][33];
  int b  = blockIdx.z;
  int p0 = blockIdx.x * 32;
  int c0 = blockIdx.y * 32;
  int tx = threadIdx.x, ty = threadIdx.y;   // (32, 8)
  const float* xb = x + (size_t)b * CDIM * 4096;
#pragma unroll
  for (int i = 0; i < 4; i++){
    int c = c0 + ty + i * 8;
    tile[ty + i * 8][tx] = xb[(size_t)c * 4096 + p0 + tx];
  }
  __syncthreads();
#pragma unroll
  for (int i = 0; i < 4; i++){
    int p = p0 + ty + i * 8;
    xf[((size_t)(b * 4096 + p)) * CDIM + c0 + tx] = f2bf(tile[tx][ty + i * 8]);
  }
}

// ---------------- K2: per-row 1/||x|| from xf bf16 ------------------------
__global__ __launch_bounds__(256) void k_rownorm(const u16* __restrict__ xf,
                                                 float* __restrict__ rinv){
  int row  = blockIdx.x * 4 + (threadIdx.x >> 6);
  int lane = threadIdx.x & 63;
  const uint4* p = (const uint4*)(xf + (size_t)row * CDIM);
  uint4 v = p[lane];
  unsigned int w[4] = {v.x, v.y, v.z, v.w};
  float s = 0.f;
#pragma unroll
  for (int i = 0; i < 4; i++){
    float a = bf2f((u16)(w[i] & 0xffffu));
    float b = bf2f((u16)(w[i] >> 16));
    s += a * a + b * b;
  }
#pragma unroll
  for (int off = 32; off; off >>= 1) s += __shfl_xor(s, off, 64);
  if (lane == 0) rinv[row] = 1.0f / fmaxf(sqrtf(s), 1e-12f);
}

// ---------------- K3: normalize noise_feature rows -> mn bf16 -------------
__global__ __launch_bounds__(256) void k_norm_rows(const float* __restrict__ in,
                                                   u16* __restrict__ out){
  int row  = blockIdx.x * 4 + (threadIdx.x >> 6);
  int lane = threadIdx.x & 63;
  const float* r = in + (size_t)row * CDIM;
  float v[8]; float s = 0.f;
#pragma unroll
  for (int i = 0; i < 8; i++){ v[i] = r[lane + i * 64]; s += v[i] * v[i]; }
#pragma unroll
  for (int off = 32; off; off >>= 1) s += __shfl_xor(s, off, 64);
  float inv = 1.0f / fmaxf(sqrtf(s), 1e-12f);
#pragma unroll
  for (int i = 0; i < 8; i++) out[(size_t)row * CDIM + lane + i * 64] = f2bf(v[i] * inv);
}

// ---------------- K3b: transpose std (1024,512) -> stdT bf16 (512,1024) ---
__global__ __launch_bounds__(256) void k_transpose_std(const float* __restrict__ sd,
                                                       u16* __restrict__ stdT){
  __shared__ float tile[32][33];
  int k0 = blockIdx.x * 32;
  int v0 = blockIdx.y * 32;
  int tx = threadIdx.x, ty = threadIdx.y;
#pragma unroll
  for (int i = 0; i < 4; i++)
    tile[ty + i * 8][tx] = sd[(size_t)(k0 + ty + i * 8) * VC + v0 + tx];
  __syncthreads();
#pragma unroll
  for (int i = 0; i < 4; i++)
    stdT[(size_t)(v0 + ty + i * 8) * KCODES + k0 + tx] = f2bf(tile[tx][ty + i * 8]);
}

// ---------------- K4: GEMM1 tiled (xf @ mn^T) + packed atomicMax argmax ---
// grid (8 ctile, 256 rtile), 256 threads. No C write.
__global__ __launch_bounds__(256) void k_gemm1_am(const u16* __restrict__ xf,
                                                  const u16* __restrict__ mn,
                                                  u64* __restrict__ packed){
  __shared__ u16 As[128 * LDP];
  __shared__ u16 Bs[128 * LDP];
  int tid  = threadIdx.x;
  int wave = tid >> 6, lane = tid & 63;
  int wr = wave >> 1, wc = wave & 1;
  int quad = lane >> 4, l15 = lane & 15;
  int c0 = blockIdx.x * 128, r0 = blockIdx.y * 128;
  int row = tid >> 1, half = tid & 1;

  f32x4 acc[4][4];
#pragma unroll
  for (int rt = 0; rt < 4; rt++)
#pragma unroll
    for (int ct = 0; ct < 4; ct++) acc[rt][ct] = (f32x4)(0.f);

  const u16* ag = xf + (size_t)(r0 + row) * CDIM + half * 32;
  const u16* bg = mn + (size_t)(c0 + row) * CDIM + half * 32;

  for (int k0 = 0; k0 < CDIM; k0 += 64){
    const uint4* asrc = (const uint4*)(ag + k0);
    const uint4* bsrc = (const uint4*)(bg + k0);
    uint4* adst = (uint4*)(As + row * LDP + half * 32);
    uint4* bdst = (uint4*)(Bs + row * LDP + half * 32);
#pragma unroll
    for (int j = 0; j < 4; j++){ adst[j] = asrc[j]; bdst[j] = bsrc[j]; }
    __syncthreads();
#pragma unroll
    for (int ks = 0; ks < 2; ks++){
      bf16x8 af[4], bf[4];
#pragma unroll
      for (int rt = 0; rt < 4; rt++)
        af[rt] = *(const bf16x8*)(As + (wr * 64 + rt * 16 + l15) * LDP + ks * 32 + quad * 8);
#pragma unroll
      for (int ct = 0; ct < 4; ct++)
        bf[ct] = *(const bf16x8*)(Bs + (wc * 64 + ct * 16 + l15) * LDP + ks * 32 + quad * 8);
#pragma unroll
      for (int rt = 0; rt < 4; rt++)
#pragma unroll
        for (int ct = 0; ct < 4; ct++)
          acc[rt][ct] = mfma16(af[rt], bf[ct], acc[rt][ct]);
    }
    __syncthreads();
  }

  // argmax epilogue: one atomicMax(u64) per row per wave-half
#pragma unroll
  for (int rt = 0; rt < 4; rt++){
#pragma unroll
    for (int q = 0; q < 4; q++){
      float bv = acc[rt][0][q];
      int   bc = c0 + wc * 64 + l15;
#pragma unroll
      for (int ct = 1; ct < 4; ct++){
        float v = acc[rt][ct][q];
        int   c = c0 + wc * 64 + ct * 16 + l15;
        if (v > bv){ bv = v; bc = c; }          // ascending c: first wins ties
      }
#pragma unroll
      for (int off = 1; off <= 8; off <<= 1){
        float ov = __shfl_xor(bv, off, 64);
        int   oc = __shfl_xor(bc, off, 64);
        if (ov > bv || (ov == bv && oc < bc)){ bv = ov; bc = oc; }
      }
      if (l15 == 0){
        int rg = r0 + wr * 64 + rt * 16 + quad * 4 + q;
        u64 key = ((u64)fkey(bv) << 32) | (unsigned int)(~(unsigned int)bc);
        atomicMax(packed + rg, key);
      }
    }
  }
}

// ---------------- K5a: decode packed -> embed_ind -------------------------
__global__ __launch_bounds__(256) void k_decode(const u64* __restrict__ packed,
                                                int* __restrict__ ind){
  int i = blockIdx.x * 256 + threadIdx.x;
  ind[i] = (int)(~(unsigned int)(packed[i] & 0xffffffffull)) & (KCODES - 1);
}

// ---------------- K5b: per-code gather segment sum (no atomics) -----------
__global__ __launch_bounds__(256) void k_gather(const int* __restrict__ ind,
                                                const u16* __restrict__ xf,
                                                float* __restrict__ esum,
                                                float* __restrict__ counts){
  __shared__ float part[4][CDIM];   // 8 KB
  __shared__ int   wcnt[4];
  int code = blockIdx.x;
  int tid = threadIdx.x, wave = tid >> 6, lane = tid & 63;
  float acc[8] = {0,0,0,0,0,0,0,0};
  int cnt = 0;
  for (int base = wave * 64; base < NROWS; base += 256){
    int match = (ind[base + lane] == code);
    u64 mask = __ballot(match);
    cnt += (int)__popcll(mask);
    while (mask){
      int b = __ffsll((long long)mask) - 1;
      mask &= mask - 1;
      int rr = base + b;
      uint4 v = *(const uint4*)(xf + (size_t)rr * CDIM + lane * 8);
      unsigned int w[4] = {v.x, v.y, v.z, v.w};
#pragma unroll
      for (int i = 0; i < 4; i++){
        acc[2 * i]     += bf2f((u16)(w[i] & 0xffffu));
        acc[2 * i + 1] += bf2f((u16)(w[i] >> 16));
      }
    }
  }
#pragma unroll
  for (int j = 0; j < 8; j++) part[wave][lane * 8 + j] = acc[j];
  if (lane == 0) wcnt[wave] = cnt;
  __syncthreads();
  for (int c = tid; c < CDIM; c += 256)
    esum[(size_t)code * CDIM + c] = part[0][c] + part[1][c] + part[2][c] + part[3][c];
  if (tid == 0) counts[code] = (float)(wcnt[0] + wcnt[1] + wcnt[2] + wcnt[3]);
}

// ---------------- K6: new_m = m*0.999 + mean*0.001; normalize -> mn2 bf16 -
__global__ __launch_bounds__(256) void k_newm(const float* __restrict__ m,
                                              const float* __restrict__ esum,
                                              const float* __restrict__ counts,
                                              u16* __restrict__ mn2){
  int row  = blockIdx.x * 4 + (threadIdx.x >> 6);
  int lane = threadIdx.x & 63;
  float cnt = counts[row];
  float sc  = 0.001f / (cnt + 1e-6f);
  float v[8]; float s = 0.f;
#pragma unroll
  for (int i = 0; i < 8; i++){
    int c = lane + i * 64;
    v[i] = m[(size_t)row * CDIM + c] * 0.999f + esum[(size_t)row * CDIM + c] * sc;
    s += v[i] * v[i];
  }
#pragma unroll
  for (int off = 32; off; off >>= 1) s += __shfl_xor(s, off, 64);
  float inv = 1.0f / fmaxf(sqrtf(s), 1e-12f);
#pragma unroll
  for (int i = 0; i < 8; i++) mn2[(size_t)row * CDIM + lane + i * 64] = f2bf(v[i] * inv);
}

// ---------------- K7: GEMM2 score2 = (xf @ mn2^T) * rinv[row] -> d_out ----
__global__ __launch_bounds__(256) void k_gemm2(const u16* __restrict__ xf,
                                               const u16* __restrict__ mn2,
                                               const float* __restrict__ rinv,
                                               float* __restrict__ score2){
  __shared__ u16 As[128 * LDP];
  __shared__ u16 Bs[128 * LDP];
  int tid  = threadIdx.x;
  int wave = tid >> 6, lane = tid & 63;
  int wr = wave >> 1, wc = wave & 1;
  int quad = lane >> 4, l15 = lane & 15;
  int c0 = blockIdx.x * 128, r0 = blockIdx.y * 128;
  int row = tid >> 1, half = tid & 1;

  f32x4 acc[4][4];
#pragma unroll
  for (int rt = 0; rt < 4; rt++)
#pragma unroll
    for (int ct = 0; ct < 4; ct++) acc[rt][ct] = (f32x4)(0.f);

  const u16* ag = xf  + (size_t)(r0 + row) * CDIM + half * 32;
  const u16* bg = mn2 + (size_t)(c0 + row) * CDIM + half * 32;

  for (int k0 = 0; k0 < CDIM; k0 += 64){
    const uint4* asrc = (const uint4*)(ag + k0);
    const uint4* bsrc = (const uint4*)(bg + k0);
    uint4* adst = (uint4*)(As + row * LDP + half * 32);
    uint4* bdst = (uint4*)(Bs + row * LDP + half * 32);
#pragma unroll
    for (int j = 0; j < 4; j++){ adst[j] = asrc[j]; bdst[j] = bsrc[j]; }
    __syncthreads();
#pragma unroll
    for (int ks = 0; ks < 2; ks++){
      bf16x8 af[4], bf[4];
#pragma unroll
      for (int rt = 0; rt < 4; rt++)
        af[rt] = *(const bf16x8*)(As + (wr * 64 + rt * 16 + l15) * LDP + ks * 32 + quad * 8);
#pragma unroll
      for (int ct = 0; ct < 4; ct++)
        bf[ct] = *(const bf16x8*)(Bs + (wc * 64 + ct * 16 + l15) * LDP + ks * 32 + quad * 8);
#pragma unroll
      for (int rt = 0; rt < 4; rt++)
#pragma unroll
        for (int ct = 0; ct < 4; ct++)
          acc[rt][ct] = mfma16(af[rt], bf[ct], acc[rt][ct]);
    }
    __syncthreads();
  }
#pragma unroll
  for (int rt = 0; rt < 4; rt++){
#pragma unroll
    for (int q = 0; q < 4; q++){
      int grow = r0 + wr * 64 + rt * 16 + quad * 4 + q;
      float rv = rinv[grow];
#pragma unroll
      for (int ct = 0; ct < 4; ct++){
        int gcol = c0 + wc * 64 + ct * 16 + l15;
        score2[(size_t)grow * KCODES + gcol] = acc[rt][ct][q] * rv;
      }
    }
  }
}

// ---------------- K8: softmax stats per row of score2 ---------------------
__global__ __launch_bounds__(256) void k_softstats(const float* __restrict__ score2,
                                                   float* __restrict__ rowmax,
                                                   float* __restrict__ rsinv){
  int row = blockIdx.x, tid = threadIdx.x;
  int wave = tid >> 6, lane = tid & 63;
  float4 v = ((const float4*)(score2 + (size_t)row * KCODES))[tid];
  float mx = fmaxf(fmaxf(v.x, v.y), fmaxf(v.z, v.w));
#pragma unroll
  for (int off = 32; off; off >>= 1) mx = fmaxf(mx, __shfl_xor(mx, off, 64));
  __shared__ float red[4], red2[4];
  if (lane == 0) red[wave] = mx;
  __syncthreads();
  mx = fmaxf(fmaxf(red[0], red[1]), fmaxf(red[2], red[3]));
  float s = __expf(v.x - mx) + __expf(v.y - mx) + __expf(v.z - mx) + __expf(v.w - mx);
#pragma unroll
  for (int off = 32; off; off >>= 1) s += __shfl_xor(s, off, 64);
  if (lane == 0) red2[wave] = s;
  __syncthreads();
  if (tid == 0){ rowmax[row] = mx; rsinv[row] = 1.0f / (red2[0] + red2[1] + red2[2] + red2[3]); }
}

// ---------------- K9: out = softmax(score2) @ std  (128x256 tile, 512 thr)
__global__ __launch_bounds__(512) void k_gemm3(const float* __restrict__ score2,
                                               const float* __restrict__ rowmax,
                                               const float* __restrict__ rsinv,
                                               const u16* __restrict__ stdT,
                                               float* __restrict__ out){
  __shared__ u16 As[128 * LDP];   // 18 KB
  __shared__ u16 Bs[256 * LDP];   // 36 KB
  int tid  = threadIdx.x;
  int wave = tid >> 6, lane = tid & 63;
  int wr = wave >> 2, wcol = wave & 3;          // 2 x 4 wave grid
  int quad = lane >> 4, l15 = lane & 15;
  int c0 = blockIdx.x * 256, r0 = blockIdx.y * 128;
  int arow = tid >> 2, aq = tid & 3;            // A: 4 thr/row, 16 elems each
  int brow = tid >> 1, bhalf = tid & 1;         // B: 2 thr/row, 32 elems each

  float rmax = rowmax[r0 + arow];
  float rs   = rsinv [r0 + arow];

  f32x4 acc[4][4];
#pragma unroll
  for (int rt = 0; rt < 4; rt++)
#pragma unroll
    for (int ct = 0; ct < 4; ct++) acc[rt][ct] = (f32x4)(0.f);

  const float* ag = score2 + (size_t)(r0 + arow) * KCODES + aq * 16;
  const u16*   bg = stdT   + (size_t)(c0 + brow) * KCODES + bhalf * 32;

  for (int k0 = 0; k0 < KCODES; k0 += 64){
#pragma unroll
    for (int j = 0; j < 2; j++){
      float4 a = *(const float4*)(ag + k0 + j * 8);
      float4 b = *(const float4*)(ag + k0 + j * 8 + 4);
      uint4 o;
      o.x = pack2(f2bf(__expf(a.x - rmax) * rs), f2bf(__expf(a.y - rmax) * rs));
      o.y = pack2(f2bf(__expf(a.z - rmax) * rs), f2bf(__expf(a.w - rmax) * rs));
      o.z = pack2(f2bf(__expf(b.x - rmax) * rs), f2bf(__expf(b.y - rmax) * rs));
      o.w = pack2(f2bf(__expf(b.z - rmax) * rs), f2bf(__expf(b.w - rmax) * rs));
      *(uint4*)(As + arow * LDP + aq * 16 + j * 8) = o;
    }
#pragma unroll
    for (int j = 0; j < 4; j++)
      *(uint4*)(Bs + brow * LDP + bhalf * 32 + j * 8) =
          *(const uint4*)(bg + k0 + j * 8);
    __syncthreads();
#pragma unroll
    for (int ks = 0; ks < 2; ks++){
      bf16x8 af[4], bf[4];
#pragma unroll
      for (int rt = 0; rt < 4; rt++)
        af[rt] = *(const bf16x8*)(As + (wr * 64 + rt * 16 + l15) * LDP + ks * 32 + quad * 8);
#pragma unroll
      for (int ct = 0; ct < 4; ct++)
        bf[ct] = *(const bf16x8*)(Bs + (wcol * 64 + ct * 16 + l15) * LDP + ks * 32 + quad * 8);
#pragma unroll
      for (int rt = 0; rt < 4; rt++)
#pragma unroll
        for (int ct = 0; ct < 4; ct++)
          acc[rt][ct] = mfma16(af[rt], bf[ct], acc[rt][ct]);
    }
    __syncthreads();
  }
#pragma unroll
  for (int rt = 0; rt < 4; rt++){
#pragma unroll
    for (int q = 0; q < 4; q++){
      int grow = r0 + wr * 64 + rt * 16 + quad * 4 + q;
#pragma unroll
      for (int ct = 0; ct < 4; ct++){
        int gcol = c0 + wcol * 64 + ct * 16 + l15;
        out[(size_t)grow * VC + gcol] = acc[rt][ct][q];
      }
    }
  }
}

// ---------------- launch ---------------------------------------------------
extern "C" void kernel_launch(void* const* d_in, const int* in_sizes, int n_in,
                              void* d_out, int out_size, void* d_ws, size_t ws_size,
                              hipStream_t stream){
  (void)in_sizes; (void)n_in; (void)out_size; (void)ws_size;
  const float* x      = (const float*)d_in[0];
  const float* m      = (const float*)d_in[1];
  const float* stdmat = (const float*)d_in[2];
  float* out    = (float*)d_out;
  float* score2 = out + (size_t)NROWS * VC;     // outputs: (out, score2)

  char* ws = (char*)d_ws;
  u16*   xf     = (u16*)  (ws + 0);             // 33,554,432 B
  u16*   mn     = (u16*)  (ws + 33554432);      //  1,048,576 B
  u16*   mn2    = (u16*)  (ws + 34603008);      //  1,048,576 B
  u16*   stdT   = (u16*)  (ws + 35651584);      //  1,048,576 B
  float* rinv   = (float*)(ws + 36700160);      //    131,072 B
  u64*   packed = (u64*)  (ws + 36831232);      //    262,144 B
  int*   ind    = (int*)  (ws + 37093376);      //    131,072 B
  float* esum   = (float*)(ws + 37224448);      //  2,097,152 B
  float* counts = (float*)(ws + 39321600);      //      4,096 B
  float* rowmax = (float*)(ws + 39325696);      //    131,072 B
  float* rsinv  = (float*)(ws + 39456768);      //    131,072 B

  hipMemsetAsync(packed, 0, (size_t)NROWS * 8, stream);  // key=0 is identity

  k_transpose_x  <<<dim3(128, 16, 8), dim3(32, 8), 0, stream>>>(x, xf);
  k_rownorm      <<<NROWS / 4, 256, 0, stream>>>(xf, rinv);
  k_norm_rows    <<<KCODES / 4, 256, 0, stream>>>(m, mn);
  k_transpose_std<<<dim3(32, 16), dim3(32, 8), 0, stream>>>(stdmat, stdT);
  k_gemm1_am     <<<dim3(KCODES / 128, NROWS / 128), 256, 0, stream>>>(xf, mn, packed);
  k_decode       <<<NROWS / 256, 256, 0, stream>>>(packed, ind);
  k_gather       <<<KCODES, 256, 0, stream>>>(ind, xf, esum, counts);
  k_newm         <<<KCODES / 4, 256, 0, stream>>>(m, esum, counts, mn2);
  k_gemm2        <<<dim3(KCODES / 128, NROWS / 128), 256, 0, stream>>>(xf, mn2, rinv, score2);
  k_softstats    <<<NROWS, 256, 0, stream>>>(score2, rowmax, rsinv);
  k_gemm3        <<<dim3(VC / 256, NROWS / 128), 512, 0, stream>>>(score2, rowmax, rsinv, stdT, out);
}